// Round 1
// baseline (70.751 us; speedup 1.0000x reference)
//
#include <hip/hip_runtime.h>
#include <math.h>

#define TT 60
#define BB 64
#define STR 68
#define NBINS 45

// ---------------- Kernel 1: TKE (temporal variance) ----------------
// grid: 2 inputs * 64 batches * 1024 float4 = 131072 threads = 512 blocks
__global__ __launch_bounds__(256) void tke_kernel(const float* __restrict__ preds,
                                                  const float* __restrict__ trues,
                                                  float* __restrict__ tke) {
    int gtid = blockIdx.x * 256 + threadIdx.x;
    int input = gtid >> 16;          // 65536 float4-threads per input
    int rem   = gtid & 65535;
    int b     = rem >> 10;           // batch
    int p4    = rem & 1023;          // float4 index within 64x64 image
    const float4* src  = (const float4*)(input ? trues : preds);
    const float4* base = src + (size_t)b * (TT * 2 * 1024) + p4;
    float su[4]  = {0,0,0,0}, squ[4] = {0,0,0,0};
    float sv[4]  = {0,0,0,0}, sqv[4] = {0,0,0,0};
    #pragma unroll 4
    for (int t = 0; t < TT; ++t) {
        float4 u = base[t * 2048];          // c = 0
        float4 v = base[t * 2048 + 1024];   // c = 1
        float uu[4] = {u.x, u.y, u.z, u.w};
        float vv[4] = {v.x, v.y, v.z, v.w};
        #pragma unroll
        for (int j = 0; j < 4; ++j) {
            su[j]  += uu[j];  squ[j] += uu[j] * uu[j];
            sv[j]  += vv[j];  sqv[j] += vv[j] * vv[j];
        }
    }
    const float inv = 1.0f / 60.0f;
    float o[4];
    #pragma unroll
    for (int j = 0; j < 4; ++j) {
        float mu = su[j] * inv, mv = sv[j] * inv;
        o[j] = 0.5f * ((squ[j] * inv - mu * mu) + (sqv[j] * inv - mv * mv));
    }
    float4 outv; outv.x = o[0]; outv.y = o[1]; outv.z = o[2]; outv.w = o[3];
    ((float4*)tke)[(size_t)(input * BB + b) * 1024 + p4] = outv;
}

// ---------------- Kernel 2: 2D DFT + power + radial bin sums ----------------
// one block (512 threads) per image; 128 images (64 preds then 64 trues)
__global__ __launch_bounds__(512) void dft_kernel(const float* __restrict__ tke,
                                                  float* __restrict__ binsums) {
    __shared__ __align__(16) float tke_s[64 * 64];
    __shared__ __align__(16) float Gr[64 * STR];   // stored [x][k], stride 68
    __shared__ __align__(16) float Gi[64 * STR];
    __shared__ float ctab[64], stab[64];
    __shared__ float bins_s[NBINS];

    int tid = threadIdx.x;
    int img = blockIdx.x;

    if (tid < 64) {
        float ang = (float)tid * 0.09817477042468103871f;   // 2*pi/64
        float ss, cc;
        sincosf(ang, &ss, &cc);
        ctab[tid] = cc; stab[tid] = ss;
    }
    if (tid < NBINS) bins_s[tid] = 0.0f;

    // load TKE image to LDS
    {
        const float4* src = (const float4*)(tke + (size_t)img * 4096);
        float4* dst = (float4*)tke_s;
        for (int i = tid; i < 1024; i += 512) dst[i] = src[i];
    }
    __syncthreads();

    // Stage A: G[k][x] = sum_y tke[y][x] * exp(-2pi i k y / 64)
    // thread owns k = tid>>3 (0..63), x-range x0..x0+7
    {
        int k  = tid >> 3;
        int x0 = (tid & 7) * 8;
        float gr[8] = {0,0,0,0,0,0,0,0};
        float gi[8] = {0,0,0,0,0,0,0,0};
        for (int y = 0; y < 64; ++y) {
            float4 ta = *(const float4*)&tke_s[(y << 6) + x0];
            float4 tb = *(const float4*)&tke_s[(y << 6) + x0 + 4];
            float tv[8] = {ta.x, ta.y, ta.z, ta.w, tb.x, tb.y, tb.z, tb.w};
            int idx = (k * y) & 63;
            float cc = ctab[idx], ss = stab[idx];
            #pragma unroll
            for (int j = 0; j < 8; ++j) {
                gr[j] += cc * tv[j];
                gi[j] -= ss * tv[j];
            }
        }
        #pragma unroll
        for (int j = 0; j < 8; ++j) {           // transposed store: G[x][k]
            Gr[(x0 + j) * STR + k] = gr[j];
            Gi[(x0 + j) * STR + k] = gi[j];
        }
    }
    __syncthreads();

    // Stage B: F[k][l] = sum_x G[k][x] * exp(-2pi i l x / 64); power + binning
    // thread owns l = tid>>3 (0..63), k-range k0..k0+7
    {
        int l  = tid >> 3;
        int k0 = (tid & 7) * 8;
        float fr[8] = {0,0,0,0,0,0,0,0};
        float fi[8] = {0,0,0,0,0,0,0,0};
        for (int x = 0; x < 64; ++x) {
            float4 a0 = *(const float4*)&Gr[x * STR + k0];
            float4 a1 = *(const float4*)&Gr[x * STR + k0 + 4];
            float4 b0 = *(const float4*)&Gi[x * STR + k0];
            float4 b1 = *(const float4*)&Gi[x * STR + k0 + 4];
            float ar[8] = {a0.x, a0.y, a0.z, a0.w, a1.x, a1.y, a1.z, a1.w};
            float br[8] = {b0.x, b0.y, b0.z, b0.w, b1.x, b1.y, b1.z, b1.w};
            int idx = (l * x) & 63;
            float cc = ctab[idx], ss = stab[idx];
            #pragma unroll
            for (int j = 0; j < 8; ++j) {
                fr[j] += ar[j] * cc + br[j] * ss;
                fi[j] += br[j] * cc - ar[j] * ss;
            }
        }
        float fl = (float)((l + 32) & 63) - 31.5f;
        #pragma unroll
        for (int j = 0; j < 8; ++j) {
            int k = k0 + j;
            float fk = (float)((k + 32) & 63) - 31.5f;
            float r = sqrtf(fk * fk + fl * fl);
            int bin = (int)r;
            float pw = fr[j] * fr[j] + fi[j] * fi[j];
            atomicAdd(&bins_s[bin], pw);
        }
    }
    __syncthreads();
    if (tid < NBINS) binsums[img * NBINS + tid] = bins_s[tid];
}

// ---------------- Kernel 3: MSE over azimuthal spectra ----------------
__global__ __launch_bounds__(256) void loss_kernel(const float* __restrict__ binsums,
                                                   float* __restrict__ out) {
    __shared__ int   cnt[NBINS];
    __shared__ float part[256];
    int tid = threadIdx.x;
    if (tid < NBINS) cnt[tid] = 0;
    __syncthreads();
    for (int p = tid; p < 4096; p += 256) {
        float dy = (float)(p >> 6) - 31.5f;
        float dx = (float)(p & 63) - 31.5f;
        int bin = (int)sqrtf(dy * dy + dx * dx);
        atomicAdd(&cnt[bin], 1);
    }
    __syncthreads();
    float acc = 0.0f;
    for (int j = tid; j < BB * 43; j += 256) {
        int b   = j / 43;
        int bin = j - b * 43 + 1;           // returned bins are 1..43
        float n  = (float)cnt[bin];
        float st = binsums[(BB + b) * NBINS + bin] / n;   // trues
        float sp = binsums[b * NBINS + bin] / n;          // preds
        float d  = st - sp;
        acc += d * d;
    }
    part[tid] = acc;
    __syncthreads();
    for (int s = 128; s > 0; s >>= 1) {
        if (tid < s) part[tid] += part[tid + s];
        __syncthreads();
    }
    if (tid == 0) out[0] = part[0] * (1.0f / (BB * 43.0f));
}

extern "C" void kernel_launch(void* const* d_in, const int* in_sizes, int n_in,
                              void* d_out, int out_size, void* d_ws, size_t ws_size,
                              hipStream_t stream) {
    const float* preds = (const float*)d_in[0];
    const float* trues = (const float*)d_in[1];
    float* tke     = (float*)d_ws;                  // 2*64*4096 floats = 2 MB
    float* binsums = tke + 2 * BB * 4096;           // 128*45 floats

    tke_kernel<<<512, 256, 0, stream>>>(preds, trues, tke);
    dft_kernel<<<128, 512, 0, stream>>>(tke, binsums);
    loss_kernel<<<1, 256, 0, stream>>>(binsums, (float*)d_out);
}